// Round 1
// baseline (386.392 us; speedup 1.0000x reference)
//
#include <hip/hip_runtime.h>
#include <hip/hip_bf16.h>
#include <stdint.h>

typedef float f32x4 __attribute__((ext_vector_type(4)));
typedef short s16x8 __attribute__((ext_vector_type(8)));
typedef unsigned int u32x4 __attribute__((ext_vector_type(4)));

#define MDIM 8192
#define NDIM 4096
#define KDIM 4096
#define BM 128
#define BN 128
#define BK 64
#define NT (KDIM / BK)

__device__ __forceinline__ unsigned pkbf(float lo, float hi) {
  unsigned short l = __builtin_bit_cast(unsigned short, __float2bfloat16(lo));
  unsigned short h = __builtin_bit_cast(unsigned short, __float2bfloat16(hi));
  return ((unsigned)h << 16) | (unsigned)l;
}

// f32 -> bf16 packed converter (used when ws_size is large enough)
__global__ void f32_to_bf16(const float* __restrict__ in, s16x8* __restrict__ outv, int n8) {
  int i = blockIdx.x * blockDim.x + threadIdx.x;
  if (i >= n8) return;
  const f32x4* p = (const f32x4*)in + 2 * (long)i;
  f32x4 a = p[0];
  f32x4 b = p[1];
  u32x4 t = { pkbf(a[0], a[1]), pkbf(a[2], a[3]), pkbf(b[0], b[1]), pkbf(b[2], b[3]) };
  outv[i] = __builtin_bit_cast(s16x8, t);
}

// Fused: y = x @ W^T + b  (bf16 MFMA, f32 accum), then per-group 128x128
// transform out = y_g @ Wg[g]^T + bg[g], all inside one 128x128 output tile.
template<bool BF16SRC>
__global__ __launch_bounds__(256, 2) void fused_gemm(
    const float* __restrict__ X, const float* __restrict__ W,
    const float* __restrict__ bias, const float* __restrict__ Wg,
    const float* __restrict__ bg, const s16x8* __restrict__ Xb,
    const s16x8* __restrict__ Wb, float* __restrict__ out)
{
  __shared__ __align__(16) unsigned char lds[65536];
  // main loop: sA = lds[0..16K), sB = lds[16K..32K)   ([128][64] bf16, swizzled)
  // epilogue:  sY = lds[0..32K), sWg = lds[32K..64K)  ([128][128] bf16, swizzled)

  const int tid = threadIdx.x;
  const int lane = tid & 63;
  const int wid = tid >> 6;
  const int wr = wid >> 1;   // 0..1: wave row quadrant
  const int wc = wid & 1;    // 0..1: wave col quadrant

  // XCD-aware bijective swizzle (2048 % 8 == 0)
  const int bid = blockIdx.x;
  const int swz = (bid & 7) * (2048 / 8) + (bid >> 3);
  const int bm = swz >> 5;   // 64 M-blocks
  const int bn = swz & 31;   // 32 N-blocks == group id
  const long brow = (long)bm * BM;
  const int bcol = bn * BN;

  // staging mapping: thread -> (row r0+32j, 8-elem k-chunk c8)
  const int r0 = tid >> 3;            // 0..31
  const int c8 = tid & 7;             // 0..7
  const int wsw = (r0 & 7) << 4;      // write-side swizzle (row&7 invariant under +32)

  s16x8 stA[4], stB[4];

  auto LOAD = [&](int kt) {
    #pragma unroll
    for (int j = 0; j < 4; ++j) {
      const int row = r0 + 32 * j;
      if constexpr (BF16SRC) {
        stA[j] = Xb[(((brow + row) * KDIM) + kt * BK + c8 * 8) >> 3];
        stB[j] = Wb[(((long)(bcol + row) * KDIM) + kt * BK + c8 * 8) >> 3];
      } else {
        const float* pa = X + (brow + row) * (long)KDIM + kt * BK + c8 * 8;
        f32x4 a0 = *(const f32x4*)pa;
        f32x4 a1 = *(const f32x4*)(pa + 4);
        u32x4 ta = { pkbf(a0[0], a0[1]), pkbf(a0[2], a0[3]),
                     pkbf(a1[0], a1[1]), pkbf(a1[2], a1[3]) };
        stA[j] = __builtin_bit_cast(s16x8, ta);
        const float* pb = W + (long)(bcol + row) * KDIM + kt * BK + c8 * 8;
        f32x4 b0 = *(const f32x4*)pb;
        f32x4 b1 = *(const f32x4*)(pb + 4);
        u32x4 tb = { pkbf(b0[0], b0[1]), pkbf(b0[2], b0[3]),
                     pkbf(b1[0], b1[1]), pkbf(b1[2], b1[3]) };
        stB[j] = __builtin_bit_cast(s16x8, tb);
      }
    }
  };

  auto WRITE = [&]() {
    #pragma unroll
    for (int j = 0; j < 4; ++j) {
      const int row = r0 + 32 * j;
      *(s16x8*)(lds + row * 128 + ((c8 * 16) ^ wsw)) = stA[j];
      *(s16x8*)(lds + 16384 + row * 128 + ((c8 * 16) ^ wsw)) = stB[j];
    }
  };

  f32x4 acc[4][4];
  #pragma unroll
  for (int m = 0; m < 4; ++m)
    #pragma unroll
    for (int n = 0; n < 4; ++n)
      acc[m][n] = (f32x4)0.0f;

  const int rsw = (lane & 7) << 4;        // read-side swizzle (frag rows: low3 = lane&7)
  const int kcol = (lane >> 4) << 4;      // 16 * (lane>>4) bytes
  const int fr = lane & 15;

  LOAD(0);
  for (int kt = 0; kt < NT; ++kt) {
    __syncthreads();
    WRITE();
    __syncthreads();
    if (kt + 1 < NT) LOAD(kt + 1);   // overlap next-tile loads with MFMA
    #pragma unroll
    for (int kk = 0; kk < 2; ++kk) {
      s16x8 af[4], bf[4];
      #pragma unroll
      for (int m = 0; m < 4; ++m) {
        const int row = wr * 64 + m * 16 + fr;
        af[m] = *(const s16x8*)(lds + row * 128 + ((kk * 64 + kcol) ^ rsw));
      }
      #pragma unroll
      for (int n = 0; n < 4; ++n) {
        const int row = wc * 64 + n * 16 + fr;
        bf[n] = *(const s16x8*)(lds + 16384 + row * 128 + ((kk * 64 + kcol) ^ rsw));
      }
      #pragma unroll
      for (int m = 0; m < 4; ++m)
        #pragma unroll
        for (int n = 0; n < 4; ++n)
          acc[m][n] = __builtin_amdgcn_mfma_f32_16x16x32_bf16(af[m], bf[n], acc[m][n], 0, 0, 0);
    }
  }

  // ------------- fused group-linear epilogue -------------
  __syncthreads();   // everyone done reading sA/sB

  float bv[4];
  #pragma unroll
  for (int n = 0; n < 4; ++n) bv[n] = bias[bcol + wc * 64 + n * 16 + fr];

  // write y = acc + b as bf16 into sY [128][256B], swizzled
  #pragma unroll
  for (int m = 0; m < 4; ++m) {
    #pragma unroll
    for (int n = 0; n < 4; ++n) {
      const int col = wc * 64 + n * 16 + fr;
      #pragma unroll
      for (int r = 0; r < 4; ++r) {
        const int row = wr * 64 + m * 16 + (lane >> 4) * 4 + r;
        const float y = acc[m][n][r] + bv[n];
        unsigned short h = __builtin_bit_cast(unsigned short, __float2bfloat16(y));
        *(unsigned short*)(lds + row * 256 + ((col * 2) ^ ((row & 7) << 4))) = h;
      }
    }
  }

  // cooperatively stage Wg[bn] (128x128 f32, L2-resident) as bf16 into sWg
  {
    const int rw0 = tid >> 4;   // 0..15
    const int cc = tid & 15;    // 0..15 (8-elem chunks)
    const float* wgp = Wg + (long)bn * (128 * 128);
    #pragma unroll
    for (int j = 0; j < 8; ++j) {
      const int row = rw0 + 16 * j;
      const float* p = wgp + row * 128 + cc * 8;
      f32x4 w0 = *(const f32x4*)p;
      f32x4 w1 = *(const f32x4*)(p + 4);
      u32x4 t = { pkbf(w0[0], w0[1]), pkbf(w0[2], w0[3]),
                  pkbf(w1[0], w1[1]), pkbf(w1[2], w1[3]) };
      *(s16x8*)(lds + 32768 + row * 256 + ((cc * 16) ^ ((row & 7) << 4))) = __builtin_bit_cast(s16x8, t);
    }
  }

  __syncthreads();

  f32x4 acc2[4][4];
  #pragma unroll
  for (int m = 0; m < 4; ++m)
    #pragma unroll
    for (int n = 0; n < 4; ++n)
      acc2[m][n] = (f32x4)0.0f;

  #pragma unroll
  for (int kk = 0; kk < 4; ++kk) {
    s16x8 af[4], bf[4];
    #pragma unroll
    for (int m = 0; m < 4; ++m) {
      const int row = wr * 64 + m * 16 + fr;
      af[m] = *(const s16x8*)(lds + row * 256 + ((kk * 64 + kcol) ^ rsw));
    }
    #pragma unroll
    for (int n = 0; n < 4; ++n) {
      const int row = wc * 64 + n * 16 + fr;
      bf[n] = *(const s16x8*)(lds + 32768 + row * 256 + ((kk * 64 + kcol) ^ rsw));
    }
    #pragma unroll
    for (int m = 0; m < 4; ++m)
      #pragma unroll
      for (int n = 0; n < 4; ++n)
        acc2[m][n] = __builtin_amdgcn_mfma_f32_16x16x32_bf16(af[m], bf[n], acc2[m][n], 0, 0, 0);
  }

  float bgv[4];
  #pragma unroll
  for (int n = 0; n < 4; ++n) bgv[n] = bg[bn * 128 + wc * 64 + n * 16 + fr];

  #pragma unroll
  for (int m = 0; m < 4; ++m) {
    #pragma unroll
    for (int n = 0; n < 4; ++n) {
      const int col = bcol + wc * 64 + n * 16 + fr;
      #pragma unroll
      for (int r = 0; r < 4; ++r) {
        const long row = brow + wr * 64 + m * 16 + (lane >> 4) * 4 + r;
        out[row * NDIM + col] = acc2[m][n][r] + bgv[n];
      }
    }
  }
}

extern "C" void kernel_launch(void* const* d_in, const int* in_sizes, int n_in,
                              void* d_out, int out_size, void* d_ws, size_t ws_size,
                              hipStream_t stream) {
  const float* X    = (const float*)d_in[0];
  const float* W    = (const float*)d_in[1];
  const float* bias = (const float*)d_in[2];
  const float* Wg   = (const float*)d_in[3];
  const float* bg   = (const float*)d_in[4];
  float* out = (float*)d_out;

  const size_t xElems = (size_t)MDIM * KDIM;
  const size_t wElems = (size_t)NDIM * KDIM;
  const size_t need = (xElems + wElems) * 2;

  dim3 block(256);
  dim3 grid(2048);   // 64 x 32 tiles of 128x128

  if (ws_size >= need) {
    s16x8* Xb = (s16x8*)d_ws;
    s16x8* Wb = (s16x8*)((char*)d_ws + xElems * 2);
    const int nx8 = (int)(xElems / 8);
    const int nw8 = (int)(wElems / 8);
    f32_to_bf16<<<dim3(nx8 / 256), block, 0, stream>>>(X, Xb, nx8);
    f32_to_bf16<<<dim3(nw8 / 256), block, 0, stream>>>(W, Wb, nw8);
    fused_gemm<true><<<grid, block, 0, stream>>>(X, W, bias, Wg, bg, Xb, Wb, out);
  } else {
    fused_gemm<false><<<grid, block, 0, stream>>>(X, W, bias, Wg, bg, nullptr, nullptr, out);
  }
}

// Round 2
// 293.229 us; speedup vs baseline: 1.3177x; 1.3177x over previous
//
#include <hip/hip_runtime.h>
#include <hip/hip_bf16.h>
#include <stdint.h>

typedef float f32x4 __attribute__((ext_vector_type(4)));
typedef short s16x8 __attribute__((ext_vector_type(8)));
typedef unsigned int u32x2 __attribute__((ext_vector_type(2)));
typedef unsigned int u32x4 __attribute__((ext_vector_type(4)));

#define MDIM 8192
#define NDIM 4096
#define KDIM 4096
#define NKT  64   // K-tiles of 64

__device__ __forceinline__ unsigned pkbf(float lo, float hi) {
  unsigned short l = __builtin_bit_cast(unsigned short, __float2bfloat16(lo));
  unsigned short h = __builtin_bit_cast(unsigned short, __float2bfloat16(hi));
  return ((unsigned)h << 16) | (unsigned)l;
}

__device__ __forceinline__ void gload16(const void* g, void* l) {
  __builtin_amdgcn_global_load_lds((const __attribute__((address_space(1))) int*)g,
                                   (__attribute__((address_space(3))) int*)l, 16, 0, 0);
}

// Convert f32 row-major [rows][4096] -> bf16 MFMA-fragment-subtiled layout.
// Per (row-tile rt of 256, K-tile kt of 64): 32 KB block =
//   [h:2 k-halves][f:16 row-frags][q:4 k-quads][fr:16 rows][e:8 bf16]
// so a fragment ds_read_b128 is exactly base + lane*16 (conflict-free),
// and global_load_lds stages it as a pure linear copy.
__global__ __launch_bounds__(256) void conv_tile(
    const float* __restrict__ X, const float* __restrict__ W,
    s16x8* __restrict__ wsA, s16x8* __restrict__ wsB) {
  __shared__ char lds[32768];
  const int b = blockIdx.x;
  const float* src;
  s16x8* dst;
  int bi;
  if (b < 32 * NKT) { src = X; dst = wsA; bi = b; }
  else              { src = W; dst = wsB; bi = b - 32 * NKT; }
  const int rt = bi >> 6;
  const int kt = bi & 63;
  const int tid = threadIdx.x;
  const int fr = tid >> 4;        // row within fragment
  const int c4 = (tid & 15) * 4;  // col (f32 units) within K-tile
  const int h = c4 >> 5, q = (c4 >> 3) & 3, eh = (c4 >> 2) & 1;
  #pragma unroll
  for (int f = 0; f < 16; ++f) {
    const int row = f * 16 + fr;
    f32x4 v = *(const f32x4*)(src + ((size_t)rt * 256 + row) * KDIM + kt * 64 + c4);
    u32x2 p = { pkbf(v[0], v[1]), pkbf(v[2], v[3]) };
    *(u32x2*)(lds + (h * 16 + f) * 1024 + (q * 16 + fr) * 16 + eh * 8) = p;
  }
  __syncthreads();
  const size_t ob = (size_t)bi * 2048;
  #pragma unroll
  for (int i = 0; i < 8; ++i)
    dst[ob + i * 256 + tid] = *(const s16x8*)(lds + (i * 256 + tid) * 16);
}

// 256x256x(K=4096) bf16 GEMM, 8-phase schedule, fused group-linear epilogue.
// LDS: A: [db:2][h:2] 16KB halves at 0..64K; B: same at 64K..128K.
// Epilogue reuses all 128KB as sY (256x256 bf16, fragment-subtiled).
__global__ __launch_bounds__(512, 2) void gemm256(
    const s16x8* __restrict__ wsA, const s16x8* __restrict__ wsB,
    const float* __restrict__ bias, const float* __restrict__ Wg,
    const float* __restrict__ bg, float* __restrict__ out) {
  extern __shared__ char smem[];
  const int tid = threadIdx.x;
  const int lane = tid & 63;
  const int wid = tid >> 6;      // 0..7
  const int wr = wid >> 2;       // 0..1  (wave row: 128 rows each)
  const int wc = wid & 3;        // 0..3  (wave col: 64 cols each)
  const int fr = lane & 15;
  const int q4 = lane >> 4;

  // XCD-bijective swizzle (512 % 8 == 0)
  const int bid = blockIdx.x;
  const int swz = (bid & 7) * 64 + (bid >> 3);
  const int bm = swz >> 4;       // 0..31
  const int bn = swz & 15;       // 0..15

  const size_t aBase = (size_t)bm * NKT * 2048;  // 16B-slot units
  const size_t bBase = (size_t)bn * NKT * 2048;

  auto stage = [&](int kt, int db, int isB, int h) {
    const s16x8* s = (isB ? wsB + bBase : wsA + aBase)
                     + (size_t)kt * 2048 + h * 1024 + wid * 128 + lane;
    char* d = smem + isB * 65536 + db * 32768 + h * 16384 + wid * 2048;
    gload16(s, d);
    gload16(s + 64, d + 1024);
  };

  const char* aRd = smem + wr * 8192 + lane * 16;
  const char* bRd = smem + 65536 + wc * 4096 + lane * 16;

  f32x4 acc[8][4];
  #pragma unroll
  for (int m = 0; m < 8; ++m)
    #pragma unroll
    for (int n = 0; n < 4; ++n) acc[m][n] = (f32x4)0.0f;

  s16x8 af[8], bfr[2];

#define PHASE(DB, H, NH, SKT, SDB, SOP, SH, DOVM)                              \
  {                                                                            \
    if ((NH) == 0) {                                                           \
      _Pragma("unroll")                                                        \
      for (int m = 0; m < 8; ++m)                                              \
        af[m] = *(const s16x8*)(aRd + (DB)*32768 + (H)*16384 + m * 1024);      \
    }                                                                          \
    bfr[0] = *(const s16x8*)(bRd + (DB)*32768 + (H)*16384 + (NH)*2048);        \
    bfr[1] = *(const s16x8*)(bRd + (DB)*32768 + (H)*16384 + (NH)*2048 + 1024); \
    stage(SKT, SDB, SOP, SH);                                                  \
    if (DOVM) asm volatile("s_waitcnt vmcnt(6)" ::: "memory");                 \
    __builtin_amdgcn_s_barrier();                                              \
    asm volatile("s_waitcnt lgkmcnt(0)" ::: "memory");                         \
    __builtin_amdgcn_s_setprio(1);                                             \
    _Pragma("unroll")                                                          \
    for (int m = 0; m < 8; ++m) {                                              \
      acc[m][(NH)*2] = __builtin_amdgcn_mfma_f32_16x16x32_bf16(                \
          af[m], bfr[0], acc[m][(NH)*2], 0, 0, 0);                             \
      acc[m][(NH)*2 + 1] = __builtin_amdgcn_mfma_f32_16x16x32_bf16(            \
          af[m], bfr[1], acc[m][(NH)*2 + 1], 0, 0, 0);                         \
    }                                                                          \
    __builtin_amdgcn_s_setprio(0);                                             \
    __builtin_amdgcn_s_barrier();                                              \
  }

  // Prologue: stream order t0.Ak0,Bk0,Ak1,Bk1, t1.Ak0,Bk0,Ak1; keep 3 in flight.
  stage(0, 0, 0, 0); stage(0, 0, 1, 0); stage(0, 0, 0, 1); stage(0, 0, 1, 1);
  stage(1, 1, 0, 0); stage(1, 1, 1, 0); stage(1, 1, 0, 1);
  asm volatile("s_waitcnt vmcnt(6)" ::: "memory");
  __builtin_amdgcn_s_barrier();

  for (int it = 0; it < 32; ++it) {
    const int u0 = 2 * it;
    const int k1 = u0 + 1;                       // always <= 63
    const int k2 = (u0 + 2 < NKT) ? u0 + 2 : NKT - 1;
    const int k3 = (u0 + 3 < NKT) ? u0 + 3 : NKT - 1;
    // tile u0 (db0)
    PHASE(0, 0, 0, k1, 1, 1, 1, 0)   // issue (u0+1).Bk1 -> db1
    PHASE(0, 0, 1, k2, 0, 0, 0, 0)   // (u0+2).Ak0 -> db0
    PHASE(0, 1, 0, k2, 0, 1, 0, 0)   // (u0+2).Bk0 -> db0
    PHASE(0, 1, 1, k2, 0, 0, 1, 1)   // (u0+2).Ak1 -> db0, vmcnt(6)
    // tile u0+1 (db1)
    PHASE(1, 0, 0, k2, 0, 1, 1, 0)   // (u0+2).Bk1 -> db0
    PHASE(1, 0, 1, k3, 1, 0, 0, 0)   // (u0+3).Ak0 -> db1
    PHASE(1, 1, 0, k3, 1, 1, 0, 0)   // (u0+3).Bk0 -> db1
    PHASE(1, 1, 1, k3, 1, 0, 1, 1)   // (u0+3).Ak1 -> db1, vmcnt(6)
  }
#undef PHASE

  // ---- drain, then fused group-linear epilogue ----
  asm volatile("s_waitcnt vmcnt(0)" ::: "memory");
  __builtin_amdgcn_s_barrier();

  float bv[4];
  #pragma unroll
  for (int n = 0; n < 4; ++n) bv[n] = bias[bn * 256 + wc * 64 + n * 16 + fr];

  // y = acc + bias -> bf16 into sY (fragment-subtiled [Mf:16][Kh:8][1KB])
  #pragma unroll
  for (int m = 0; m < 8; ++m) {
    #pragma unroll
    for (int n = 0; n < 4; ++n) {
      const int Kh = wc * 2 + (n >> 1);
      const int qq = (n & 1) * 2 + (fr >> 3);
      const int Mf = wr * 8 + m;
      #pragma unroll
      for (int r = 0; r < 4; ++r) {
        const int frs = q4 * 4 + r;
        const float y = acc[m][n][r] + bv[n];
        *(unsigned short*)(smem + (Mf * 8 + Kh) * 1024 + (qq * 16 + frs) * 16 + (fr & 7) * 2)
            = __builtin_bit_cast(unsigned short, __float2bfloat16(y));
      }
    }
  }
  asm volatile("s_waitcnt lgkmcnt(0)" ::: "memory");
  __builtin_amdgcn_s_barrier();

  // out_g = sY_g @ Wg[g]^T + bg ; wave (wr,wc) keeps its 128x64 sub-tile,
  // K = this wave's group's 128 cols (Kh = (wc>>1)*4 + s).
  const int g = bn * 2 + (wc >> 1);
  const float* wgb = Wg + (size_t)g * 16384;
  f32x4 acc2[8][4];
  #pragma unroll
  for (int m = 0; m < 8; ++m)
    #pragma unroll
    for (int n = 0; n < 4; ++n) acc2[m][n] = (f32x4)0.0f;

  #pragma unroll
  for (int s = 0; s < 4; ++s) {
    const int Kh = (wc >> 1) * 4 + s;
    s16x8 af2[8];
    #pragma unroll
    for (int m = 0; m < 8; ++m)
      af2[m] = *(const s16x8*)(smem + ((wr * 8 + m) * 8 + Kh) * 1024 + lane * 16);
    #pragma unroll
    for (int n = 0; n < 4; ++n) {
      const int ocl = (wc & 1) * 64 + n * 16 + fr;   // out col within group
      const float* wp = wgb + ocl * 128 + s * 32 + q4 * 8;
      f32x4 w0 = *(const f32x4*)wp;
      f32x4 w1 = *(const f32x4*)(wp + 4);
      u32x4 pw = { pkbf(w0[0], w0[1]), pkbf(w0[2], w0[3]),
                   pkbf(w1[0], w1[1]), pkbf(w1[2], w1[3]) };
      const s16x8 bfw = __builtin_bit_cast(s16x8, pw);
      #pragma unroll
      for (int m = 0; m < 8; ++m)
        acc2[m][n] = __builtin_amdgcn_mfma_f32_16x16x32_bf16(af2[m], bfw, acc2[m][n], 0, 0, 0);
    }
  }

  float bgv[4];
  #pragma unroll
  for (int n = 0; n < 4; ++n) bgv[n] = bg[bn * 256 + wc * 64 + n * 16 + fr];

  #pragma unroll
  for (int m = 0; m < 8; ++m) {
    #pragma unroll
    for (int n = 0; n < 4; ++n) {
      const int col = bn * 256 + wc * 64 + n * 16 + fr;
      #pragma unroll
      for (int r = 0; r < 4; ++r) {
        const size_t row = (size_t)bm * 256 + wr * 128 + m * 16 + q4 * 4 + r;
        out[row * NDIM + col] = acc2[m][n][r] + bgv[n];
      }
    }
  }
}

extern "C" void kernel_launch(void* const* d_in, const int* in_sizes, int n_in,
                              void* d_out, int out_size, void* d_ws, size_t ws_size,
                              hipStream_t stream) {
  const float* X    = (const float*)d_in[0];
  const float* W    = (const float*)d_in[1];
  const float* bias = (const float*)d_in[2];
  const float* Wg   = (const float*)d_in[3];
  const float* bg   = (const float*)d_in[4];
  float* out = (float*)d_out;

  s16x8* wsA = (s16x8*)d_ws;
  s16x8* wsB = wsA + ((size_t)MDIM * KDIM / 8);   // A: 64MB, B: 32MB (ws >= 100.7MB, proven round 1)

  static int lds_attr_set = 0;
  (void)lds_attr_set;
  hipFuncSetAttribute(reinterpret_cast<const void*>(gemm256),
                      hipFuncAttributeMaxDynamicSharedMemorySize, 131072);

  conv_tile<<<dim3(32 * NKT + 16 * NKT), dim3(256), 0, stream>>>(X, W, wsA, wsB);
  gemm256<<<dim3(512), dim3(512), 131072, stream>>>(wsA, wsB, bias, Wg, bg, out);
}